// Round 2
// baseline (193.400 us; speedup 1.0000x reference)
//
#include <hip/hip_runtime.h>
#include <hip/hip_bf16.h>

// DirectionalPropagation1D fused: B=16, C=64, H=256, W=256, N=4096 sequences.
// One kernel, 256 blocks x 4 waves. Block = 16 sequences (one (b, h-tile)).
// Per step w: acc = (bi+bs+bias) + Wi*feat_w + Ws*(g_w * state); state = relu.
// State lives in ping-pong LDS (bf16), exchanged across waves each step via
// __syncthreads(). feat staged per-16w-chunk in LDS; out staged in LDS and
// dumped coalesced. No workspace, no inter-kernel handoff.

typedef __attribute__((ext_vector_type(8))) short short8;
typedef __attribute__((ext_vector_type(4))) short short4v;
typedef __attribute__((ext_vector_type(2))) short short2v;
typedef __attribute__((ext_vector_type(4))) float f32x4;

union FragU { unsigned int u[4]; short8 v; };
union PkU { unsigned int u; short2v s2; };

__device__ __forceinline__ unsigned int pk2(float a, float b) {
    unsigned short lo = __bfloat16_as_ushort(__float2bfloat16(a));
    unsigned short hi = __bfloat16_as_ushort(__float2bfloat16(b));
    return (unsigned int)lo | ((unsigned int)hi << 16);
}
__device__ __forceinline__ float b2f(short x) {
    return __uint_as_float(((unsigned int)(unsigned short)x) << 16);
}

// LDS index helpers (ushort units). XOR swizzles are bijective and identical
// on write & read sides; they never touch alignment bits of the vector ops.
__device__ __forceinline__ int fsi(int w, int n, int c) {   // feat [w16][n16][c64]
    return (w * 1024 + n * 64 + c) ^ ((n & 7) << 3);
}
__device__ __forceinline__ int sti(int n, int c) {          // state [n16][c64]
    return (n * 64 + c) ^ ((n & 7) << 3);
}
__device__ __forceinline__ int ogi(int o, int n, int w) {   // out [o64][n16][w16]
    return (o * 256 + n * 16 + w) ^ ((((o >> 2) ^ (n >> 2)) & 3) << 2);
}

template<int V> struct Ic { static constexpr int value = V; };

__global__ __launch_bounds__(256) void dp_fused_kernel(
    const float* __restrict__ feat, const float* __restrict__ conf,
    const float* __restrict__ Wi, const float* __restrict__ bi,
    const float* __restrict__ Ws, const float* __restrict__ bs,
    const float* __restrict__ bias, float* __restrict__ outp)
{
    __shared__ unsigned short fs[2][16384];  // 64 KB: feat chunk, bf16, ping-pong
    __shared__ unsigned short st[2][1024];   //  4 KB: state, bf16, ping-pong by step
    __shared__ unsigned short og[16384];     // 32 KB: out staging, bf16

    const int tid = threadIdx.x;
    const int lane = tid & 63;
    const int t = tid >> 6;                  // wave id = o-tile index
    const int l15 = lane & 15, g4 = lane >> 4;
    const int nb = blockIdx.x;
    const int b = nb >> 4, h0 = (nb & 15) * 16;

    // A fragments: lane holds M[16t + l15][32hh + g4*8 + j], j=0..7  (validated r1)
    FragU Ai[2], As[2];
    #pragma unroll
    for (int hh = 0; hh < 2; ++hh) {
        const float* si = Wi + (16 * t + l15) * 64 + 32 * hh + g4 * 8;
        const float* ss = Ws + (16 * t + l15) * 64 + 32 * hh + g4 * 8;
        #pragma unroll
        for (int d = 0; d < 4; ++d) {
            Ai[hh].u[d] = pk2(si[2 * d], si[2 * d + 1]);
            As[hh].u[d] = pk2(ss[2 * d], ss[2 * d + 1]);
        }
    }
    // folded bias for C rows o = 16t + 4g4 + r (all-step constant)
    float binit[4];
    #pragma unroll
    for (int r = 0; r < 4; ++r) {
        int o = 16 * t + 4 * g4 + r;
        binit[r] = bi[o] + bs[o] + bias[o];
    }

    const float* fb = feat + (size_t)b * 64 * 65536 + (size_t)h0 * 256; // +c*65536+n*256+w
    const float* gb = conf + ((size_t)(b * 256) + h0 + l15) * 256;      // gate row, n=l15

    // feat chunk staging registers: thread owns 2 (c-pair, n) rows x 16 w
    f32x4 fst[2][2][4];   // [k][row01][w-quad] -- all statically indexed
    auto issue_feat = [&](int w0) {
        #pragma unroll
        for (int k = 0; k < 2; ++k) {
            int p = tid + 256 * k; int cp = p >> 4; int n = p & 15;
            const float* base = fb + (size_t)(2 * cp) * 65536 + n * 256 + w0;
            #pragma unroll
            for (int row = 0; row < 2; ++row)
                #pragma unroll
                for (int j = 0; j < 4; ++j)
                    fst[k][row][j] = *(const f32x4*)(base + row * 65536 + j * 4);
        }
    };
    auto write_fs = [&](int buf) {
        #pragma unroll
        for (int k = 0; k < 2; ++k) {
            int p = tid + 256 * k; int cp = p >> 4; int n = p & 15;
            #pragma unroll
            for (int j = 0; j < 4; ++j)
                #pragma unroll
                for (int e = 0; e < 4; ++e) {
                    PkU pk; pk.u = pk2(fst[k][0][j][e], fst[k][1][j][e]);
                    *(short2v*)&fs[buf][fsi(j * 4 + e, n, 2 * cp)] = pk.s2;
                }
        }
    };
    auto dump = [&](int wprev) {   // coalesced: 16 lines / inst, full 64B lines
        const int n = lane >> 2, wq = lane & 3;
        #pragma unroll
        for (int k = 0; k < 16; ++k) {
            const int o = 16 * t + k;
            short4v d = *(const short4v*)&og[ogi(o, n, wq * 4)];
            f32x4 o4 = { b2f(d.x), b2f(d.y), b2f(d.z), b2f(d.w) };
            *(f32x4*)(outp + ((size_t)(b * 64 + o) * 256 + h0 + n) * 256 + wprev + wq * 4) = o4;
        }
    };

    // gate registers, ping-pong by chunk parity (statically selected)
    f32x4 gqA[4], gqB[4]; float glA, glB;

    // ---- prologue ----
    issue_feat(0);
    #pragma unroll
    for (int q = 0; q < 4; ++q) gqA[q] = *(const f32x4*)(gb + q * 4);
    glA = gb[16];
    { short4v z = {0, 0, 0, 0}; *(short4v*)&st[0][tid * 4] = z; }
    write_fs(0);
    __syncthreads();

    auto run_chunk = [&](auto pc, int cc) {
        constexpr int P = decltype(pc)::value;
        f32x4 (&gqc)[4] = P ? gqB : gqA;
        f32x4 (&gqn)[4] = P ? gqA : gqB;
        float &glc = P ? glB : glA;
        float &gln = P ? glA : glB;
        const int w0 = cc * 16;
        float curE[4];
        #pragma unroll
        for (int u = 0; u < 16; ++u) {
            // dump previous chunk BEFORE any og write of this chunk (u==0 only)
            if (u == 0 && cc > 0) dump(w0 - 16);

            short8 F0 = *(const short8*)&fs[P][fsi(u, l15, g4 * 8)];
            short8 F1 = *(const short8*)&fs[P][fsi(u, l15, 32 + g4 * 8)];
            short8 S0 = *(const short8*)&st[u & 1][sti(l15, g4 * 8)];
            short8 S1 = *(const short8*)&st[u & 1][sti(l15, 32 + g4 * 8)];
            f32x4 acc = { binit[0], binit[1], binit[2], binit[3] };
            acc = __builtin_amdgcn_mfma_f32_16x16x32_bf16(Ai[0].v, F0, acc, 0, 0, 0);
            acc = __builtin_amdgcn_mfma_f32_16x16x32_bf16(Ai[1].v, F1, acc, 0, 0, 0);
            acc = __builtin_amdgcn_mfma_f32_16x16x32_bf16(As[0].v, S0, acc, 0, 0, 0);
            acc = __builtin_amdgcn_mfma_f32_16x16x32_bf16(As[1].v, S1, acc, 0, 0, 0);
            float cur0 = fmaxf(acc[0], 0.f), cur1 = fmaxf(acc[1], 0.f);
            float cur2 = fmaxf(acc[2], 0.f), cur3 = fmaxf(acc[3], 0.f);

            if (u == 0 && cc < 15) issue_feat(w0 + 16);        // next-chunk prefetch
            if (u == 2 && cc < 15) {                           // next-chunk gates
                #pragma unroll
                for (int q = 0; q < 4; ++q)
                    gqn[q] = *(const f32x4*)(gb + w0 + 16 + q * 4);
                int gi = w0 + 32; if (gi > 255) gi = 255;      // value unused at w=255
                gln = gb[gi];
            }

            // out staging: pack w-pairs, write b32 on odd steps
            if ((u & 1) == 0) {
                curE[0] = cur0; curE[1] = cur1; curE[2] = cur2; curE[3] = cur3;
            } else {
                const float cc4[4] = { cur0, cur1, cur2, cur3 };
                #pragma unroll
                for (int r = 0; r < 4; ++r) {
                    PkU pk; pk.u = pk2(curE[r], cc4[r]);
                    *(short2v*)&og[ogi(16 * t + 4 * g4 + r, l15, u - 1)] = pk.s2;
                }
            }

            if (u == 14 && cc < 15) write_fs(P ^ 1);           // stage next feat chunk

            // gated state write for step w+1 (skip only at the very last step)
            if (!(cc == 15 && u == 15)) {
                float gv = (u < 15) ? gqc[(u + 1) >> 2][(u + 1) & 3] : glc;
                PkU a, c;
                a.u = pk2(cur0 * gv, cur1 * gv);
                c.u = pk2(cur2 * gv, cur3 * gv);
                short4v sv = { a.s2.x, a.s2.y, c.s2.x, c.s2.y };
                *(short4v*)&st[(u + 1) & 1][sti(l15, 16 * t + 4 * g4)] = sv;
            }
            __syncthreads();
        }
    };

    #pragma unroll 1
    for (int c2 = 0; c2 < 8; ++c2) {
        run_chunk(Ic<0>{}, c2 * 2);
        run_chunk(Ic<1>{}, c2 * 2 + 1);
    }
    dump(240);   // final chunk
}

extern "C" void kernel_launch(void* const* d_in, const int* in_sizes, int n_in,
                              void* d_out, int out_size, void* d_ws, size_t ws_size,
                              hipStream_t stream) {
    const float* feat = (const float*)d_in[0];
    const float* conf = (const float*)d_in[1];
    const float* Wi   = (const float*)d_in[2];
    const float* bi   = (const float*)d_in[3];
    const float* Ws   = (const float*)d_in[4];
    const float* bs   = (const float*)d_in[5];
    const float* bias = (const float*)d_in[6];
    float* out = (float*)d_out;
    (void)d_ws; (void)ws_size; (void)in_sizes; (void)n_in; (void)out_size;

    dp_fused_kernel<<<256, 256, 0, stream>>>(feat, conf, Wi, bi, Ws, bs, bias, out);
}